// Round 4
// baseline (39503.339 us; speedup 1.0000x reference)
//
#include <hip/hip_runtime.h>
#include <hip/hip_cooperative_groups.h>

namespace cg = cooperative_groups;

// DecoderModule: B=64, T=128, S=512, E=256, H=512, 2H=1024, GRU_IN=1280
// fp32 I/O; bf16 MFMA internally. One cooperative persistent kernel runs the
// 128-step loop with 4 grid.sync()/step. GEMMs: direct-from-global MFMA
// (16x64 tile per wave, split-K partials, no LDS staging).

#define LDSS 40
#define GRID 512

typedef short bf16x8 __attribute__((ext_vector_type(8)));
typedef float f32x4 __attribute__((ext_vector_type(4)));

__device__ inline ushort f2b(float f) {
    unsigned int u = __float_as_uint(f);
    return (ushort)((u + 0x7FFFu + ((u >> 16) & 1u)) >> 16);
}
__device__ inline float b2f(ushort u) {
    return __uint_as_float(((unsigned int)u) << 16);
}
__device__ inline float fast_tanh(float x) {
    x = fminf(fmaxf(x, -15.f), 15.f);
    float ex = __expf(2.f * x);
    return (ex - 1.f) / (ex + 1.f);
}
__device__ inline bf16x8 packA(const float* p, float s) {
    float4 f0 = *(const float4*)p;
    float4 f1 = *(const float4*)(p + 4);
    bf16x8 r;
    r[0] = (short)f2b(f0.x * s); r[1] = (short)f2b(f0.y * s);
    r[2] = (short)f2b(f0.z * s); r[3] = (short)f2b(f0.w * s);
    r[4] = (short)f2b(f1.x * s); r[5] = (short)f2b(f1.y * s);
    r[6] = (short)f2b(f1.z * s); r[7] = (short)f2b(f1.w * s);
    return r;
}

struct PArgs {
    const float* trg; const float* encf; const ushort* enc_b; int useb;
    const int* mask; const ushort* pk; const float* wE;
    const ushort* Wq; const ushort* Whh; const ushort* Wih; const ushort* Wpre;
    const float* bih; const float* bhh;
    float* h; ushort* h_b;
    float* q_part;   // [4][64][512]
    float* gh_part;  // [4][64][1536]
    float* pre_part; // [14][64][512]
    float* gx_part;  // [10][64][1536]
    float* ctx;      // [2][64][1024]
    float* denom;    // [2][64]
    float* out_states; float* out_hidden; float* out_pre;
};

// one wave: D[16m x 64n] += A[16,k] * W[n,k]^T over k in [kb,ke)
// layouts (verified R2/R3): A[m=lrow][k=quad*8+j], B[n=lrow][k=quad*8+j],
// D[row=quad*4+r][col=nf*16+lrow]
template <class AG>
__device__ __forceinline__ void wave_tile(f32x4 acc[4], AG getA,
                                          const ushort* __restrict__ W, int ldw,
                                          int n0, int kb, int ke, int lrow, int quad)
{
    for (int k = kb; k < ke; k += 32) {
        int kk = k + quad * 8;
        bf16x8 av = getA(kk);
        const ushort* wp = W + (long)(n0 + lrow) * ldw + kk;
#pragma unroll
        for (int nf = 0; nf < 4; nf++) {
            bf16x8 bv = *(const bf16x8*)(wp + (long)(nf * 16) * ldw);
            acc[nf] = __builtin_amdgcn_mfma_f32_16x16x32_bf16(av, bv, acc[nf], 0, 0, 0);
        }
    }
}

__device__ __forceinline__ void store_part(float* P, f32x4 acc[4],
                                           int m0, int n0, int ldc, int lrow, int quad)
{
#pragma unroll
    for (int nf = 0; nf < 4; nf++)
#pragma unroll
        for (int r = 0; r < 4; r++)
            P[(m0 + quad * 4 + r) * ldc + (n0 + nf * 16 + lrow)] = acc[nf][r];
}

// Phase A: q [gw 0..127], gh [128..511], pre(t-1) [512..959]
__device__ __forceinline__ void phaseA(const PArgs& a, int t, int gw, int lrow, int quad)
{
    f32x4 acc[4];
#pragma unroll
    for (int i = 0; i < 4; i++) acc[i] = f32x4{0.f, 0.f, 0.f, 0.f};
    if (gw < 128) {
        int nt = gw & 7, ms = (gw >> 3) & 3, kc = gw >> 5;
        int m0 = ms * 16, n0 = nt * 64, kb = kc * 128;
        const ushort* A = a.h_b + (m0 + lrow) * 512;
        wave_tile(acc, [&](int kk) { return *(const bf16x8*)(A + kk); },
                  a.Wq, 512, n0, kb, kb + 128, lrow, quad);
        store_part(a.q_part + kc * 32768, acc, m0, n0, 512, lrow, quad);
    } else if (gw < 512) {
        int idx = gw - 128;
        int nt = idx % 24, ms = (idx / 24) & 3, kc = idx / 96;
        int m0 = ms * 16, n0 = nt * 64, kb = kc * 128;
        const ushort* A = a.h_b + (m0 + lrow) * 512;
        wave_tile(acc, [&](int kk) { return *(const bf16x8*)(A + kk); },
                  a.Whh, 512, n0, kb, kb + 128, lrow, quad);
        store_part(a.gh_part + kc * 98304, acc, m0, n0, 1536, lrow, quad);
    } else if (gw < 960) {
        if (t < 1) return;
        int idx = gw - 512;
        int nt = idx & 7, ms = (idx >> 3) & 3, kc = idx >> 5;   // kc 0..13
        int m0 = ms * 16, n0 = nt * 64, kb = kc * 128;
        int m = m0 + lrow;
        int par1 = (t - 1) & 1;
        if (kc < 2) {          // x_{t-1}: k in [0,256)
            const float* src = a.trg + ((long)m * 128 + (t - 1)) * 256;
            wave_tile(acc, [&](int kk) { return packA(src + kk, 1.f); },
                      a.Wpre, 1792, n0, kb, kb + 128, lrow, quad);
        } else if (kc < 6) {   // h_{t-1}: k in [256,768)
            const ushort* src = a.h_b + m * 512 - 256;
            wave_tile(acc, [&](int kk) { return *(const bf16x8*)(src + kk); },
                      a.Wpre, 1792, n0, kb, kb + 128, lrow, quad);
        } else {               // ctx_{t-1}: k in [768,1792)
            float inv = 1.f / a.denom[par1 * 64 + m];
            const float* src = a.ctx + par1 * 65536 + m * 1024 - 768;
            wave_tile(acc, [&](int kk) { return packA(src + kk, inv); },
                      a.Wpre, 1792, n0, kb, kb + 128, lrow, quad);
        }
        store_part(a.pre_part + kc * 32768, acc, m0, n0, 512, lrow, quad);
    }
}

// Phase B: fused attention. block = (b, s-chunk of 64). Computes e, p=exp(e),
// accumulates denom + p*enc into ctx[par] (atomics, parity-double-buffered).
__device__ __forceinline__ void phaseB(const PArgs& a, int t, int bid, int tid,
                                       int wave, int lane,
                                       float* sh_q, float* sh_w, float* sh_p, float* sh_red)
{
    int b = bid >> 3, sc = bid & 7;
    int par = t & 1;
    for (int i = tid; i < 512; i += 256) {
        const float* qp = a.q_part + b * 512 + i;
        sh_q[i] = qp[0] + qp[32768] + qp[65536] + qp[98304];
        sh_w[i] = a.wE[i];
    }
    __syncthreads();
    float wsum = 0.f;
    for (int i = 0; i < 16; i++) {
        int s = sc * 64 + wave * 16 + i;
        const ushort* pkp = a.pk + ((long)(b * 512 + s) << 9) + lane * 8;
        bf16x8 pv = *(const bf16x8*)pkp;
        float acc = 0.f;
#pragma unroll
        for (int j = 0; j < 8; j++)
            acc += fast_tanh(sh_q[lane * 8 + j] + b2f((ushort)pv[j])) * sh_w[lane * 8 + j];
#pragma unroll
        for (int off = 32; off; off >>= 1) acc += __shfl_xor(acc, off);
        if (lane == 0) {
            float p = (a.mask[b * 512 + s] != 0) ? __expf(acc) : 0.f;
            sh_p[wave * 16 + i] = p;
            wsum += p;
        }
    }
    if (lane == 0) sh_red[wave] = wsum;
    __syncthreads();
    if (tid == 0)
        atomicAdd(&a.denom[par * 64 + b], sh_red[0] + sh_red[1] + sh_red[2] + sh_red[3]);
    int d = tid * 4;
    float c0 = 0.f, c1 = 0.f, c2 = 0.f, c3 = 0.f;
    if (a.useb) {
        const ushort* ep = a.enc_b + ((long)b << 19) + (long)(sc * 64) * 1024 + d;
#pragma unroll 4
        for (int s2 = 0; s2 < 64; s2++) {
            float p = sh_p[s2];
            ushort4 ev = *(const ushort4*)(ep + (long)s2 * 1024);
            c0 += p * b2f(ev.x); c1 += p * b2f(ev.y);
            c2 += p * b2f(ev.z); c3 += p * b2f(ev.w);
        }
    } else {
        const float* ep = a.encf + ((long)b << 19) + (long)(sc * 64) * 1024 + d;
#pragma unroll 4
        for (int s2 = 0; s2 < 64; s2++) {
            float p = sh_p[s2];
            float4 ev = *(const float4*)(ep + (long)s2 * 1024);
            c0 += p * ev.x; c1 += p * ev.y; c2 += p * ev.z; c3 += p * ev.w;
        }
    }
    float* cp = a.ctx + par * 65536 + b * 1024 + d;
    atomicAdd(cp, c0); atomicAdd(cp + 1, c1);
    atomicAdd(cp + 2, c2); atomicAdd(cp + 3, c3);
}

// Phase C: gx = [x_t, ctx_t] @ Wih^T, split-K 10x128, gw 0..959
__device__ __forceinline__ void phaseC(const PArgs& a, int t, int gw, int lrow, int quad)
{
    if (gw >= 960) return;
    f32x4 acc[4];
#pragma unroll
    for (int i = 0; i < 4; i++) acc[i] = f32x4{0.f, 0.f, 0.f, 0.f};
    int nt = gw % 24, ms = (gw / 24) & 3, kc = gw / 96;  // kc 0..9
    int m0 = ms * 16, n0 = nt * 64, kb = kc * 128;
    int m = m0 + lrow;
    int par = t & 1;
    if (kc < 2) {      // x_t: k in [0,256)
        const float* src = a.trg + ((long)m * 128 + t) * 256;
        wave_tile(acc, [&](int kk) { return packA(src + kk, 1.f); },
                  a.Wih, 1280, n0, kb, kb + 128, lrow, quad);
    } else {           // ctx: k in [256,1280)
        float inv = 1.f / a.denom[par * 64 + m];
        const float* src = a.ctx + par * 65536 + m * 1024 - 256;
        wave_tile(acc, [&](int kk) { return packA(src + kk, inv); },
                  a.Wih, 1280, n0, kb, kb + 128, lrow, quad);
    }
    store_part(a.gx_part + kc * 98304, acc, m0, n0, 1536, lrow, quad);
}

// Phase D: gates + h update + outputs + zero next-parity ctx/denom
__device__ __forceinline__ void phaseD(const PArgs& a, int t, int bid, int tid)
{
    if (bid < 128) {
        int idx = bid * 256 + tid;        // 0..32767
        int b = idx >> 9, j = idx & 511;
        float rh = 0.f, zh = 0.f, nh = 0.f;
        const float* ghp = a.gh_part + b * 1536 + j;
#pragma unroll
        for (int kc = 0; kc < 4; kc++) {
            rh += ghp[kc * 98304];
            zh += ghp[kc * 98304 + 512];
            nh += ghp[kc * 98304 + 1024];
        }
        float rx = 0.f, zx = 0.f, nx = 0.f;
        const float* gxp = a.gx_part + b * 1536 + j;
#pragma unroll
        for (int kc = 0; kc < 10; kc++) {
            rx += gxp[kc * 98304];
            zx += gxp[kc * 98304 + 512];
            nx += gxp[kc * 98304 + 1024];
        }
        rx += a.bih[j]; zx += a.bih[j + 512]; nx += a.bih[j + 1024];
        rh += a.bhh[j]; zh += a.bhh[j + 512]; nh += a.bhh[j + 1024];
        float r = 1.f / (1.f + __expf(-(rx + rh)));
        float z = 1.f / (1.f + __expf(-(zx + zh)));
        float n = fast_tanh(nx + r * nh);
        float hn = (1.f - z) * n + z * a.h[idx];
        a.h[idx] = hn;
        a.h_b[idx] = f2b(hn);
        a.out_states[((long)b * 128 + t) * 512 + j] = hn;
        if (t >= 1) {
            float pr = 0.f;
            const float* pp = a.pre_part + b * 512 + j;
#pragma unroll
            for (int kc = 0; kc < 14; kc++) pr += pp[kc * 32768];
            a.out_pre[((long)b * 128 + (t - 1)) * 512 + j] = pr;
        }
    }
    int gid = bid * 256 + tid;
    int np = (t + 1) & 1;
    if (gid < 65536) a.ctx[np * 65536 + gid] = 0.f;
    if (gid < 64) a.denom[np * 64 + gid] = 0.f;
}

__device__ __forceinline__ void finalD(const PArgs& a, int bid, int tid)
{
    if (bid < 128) {
        int idx = bid * 256 + tid;
        int b = idx >> 9, j = idx & 511;
        float pr = 0.f;
        const float* pp = a.pre_part + b * 512 + j;
#pragma unroll
        for (int kc = 0; kc < 14; kc++) pr += pp[kc * 32768];
        a.out_pre[((long)b * 128 + 127) * 512 + j] = pr;
        a.out_hidden[idx] = a.h[idx];
    }
}

__global__ __launch_bounds__(256, 2) void decoder_coop(PArgs a)
{
    cg::grid_group grid = cg::this_grid();
    __shared__ float sh_q[512];
    __shared__ float sh_w[512];
    __shared__ float sh_p[64];
    __shared__ float sh_red[16];
    const int bid = blockIdx.x, tid = threadIdx.x;
    const int wave = tid >> 6, lane = tid & 63;
    const int lrow = lane & 15, quad = lane >> 4;
    const int gw = bid * 4 + wave;
    for (int t = 0; t < 128; t++) {
        phaseA(a, t, gw, lrow, quad);
        grid.sync();
        phaseB(a, t, bid, tid, wave, lane, sh_q, sh_w, sh_p, sh_red);
        grid.sync();
        phaseC(a, t, gw, lrow, quad);
        grid.sync();
        phaseD(a, t, bid, tid);
        grid.sync();
    }
    phaseA(a, 128, gw, lrow, quad);   // pre(127) partials (q/gh redone, unused)
    grid.sync();
    finalD(a, bid, tid);
}

// --------- fallback wrappers (used only if cooperative launch fails) ---------
__global__ __launch_bounds__(256, 2) void kA(PArgs a, int t) {
    int lane = threadIdx.x & 63;
    phaseA(a, t, blockIdx.x * 4 + (threadIdx.x >> 6), lane & 15, lane >> 4);
}
__global__ __launch_bounds__(256, 2) void kB(PArgs a, int t) {
    __shared__ float sh_q[512];
    __shared__ float sh_w[512];
    __shared__ float sh_p[64];
    __shared__ float sh_red[16];
    phaseB(a, t, blockIdx.x, threadIdx.x, threadIdx.x >> 6, threadIdx.x & 63,
           sh_q, sh_w, sh_p, sh_red);
}
__global__ __launch_bounds__(256, 2) void kC(PArgs a, int t) {
    int lane = threadIdx.x & 63;
    phaseC(a, t, blockIdx.x * 4 + (threadIdx.x >> 6), lane & 15, lane >> 4);
}
__global__ __launch_bounds__(256, 2) void kD(PArgs a, int t) {
    phaseD(a, t, blockIdx.x, threadIdx.x);
}
__global__ __launch_bounds__(256, 2) void kF(PArgs a) {
    finalD(a, blockIdx.x, threadIdx.x);
}

// --------------------------- prelude kernels ---------------------------------
__global__ void f2b4_kernel(const float4* __restrict__ in, ushort4* __restrict__ out, int n4) {
    int i = blockIdx.x * blockDim.x + threadIdx.x;
    int stride = gridDim.x * blockDim.x;
    for (; i < n4; i += stride) {
        float4 v = in[i];
        ushort4 o;
        o.x = f2b(v.x); o.y = f2b(v.y); o.z = f2b(v.z); o.w = f2b(v.w);
        out[i] = o;
    }
}

template <bool AF32>
__device__ inline void gemm64x64(const void* __restrict__ Av, const ushort* __restrict__ B,
                                 ushort* As, ushort* Bs, int lda, int ldb, int K,
                                 float* Cf, ushort* Cb, long ldc, long m0, long n0)
{
    const int tid = threadIdx.x;
    const int wave = tid >> 6, lane = tid & 63;
    const int row = tid >> 2, kcol = (tid & 3) * 8;
    const int lrow = lane & 15, quad = lane >> 4;
    f32x4 acc[4];
#pragma unroll
    for (int i = 0; i < 4; i++) acc[i] = f32x4{0.f, 0.f, 0.f, 0.f};
    const ushort* Ab  = (const ushort*)Av + (m0 + row) * (long)lda + kcol;
    const float*  Afp = (const float*)Av + (m0 + row) * (long)lda + kcol;
    const ushort* Bp  = B + (n0 + row) * (long)ldb + kcol;
    ushort* AsW = As + row * LDSS + kcol;
    ushort* BsW = Bs + row * LDSS + kcol;
    const ushort* AsR = As + (wave * 16 + lrow) * LDSS + quad * 8;
    const ushort* BsR = Bs + lrow * LDSS + quad * 8;
    for (int k0 = 0; k0 < K; k0 += 32) {
        uint4 av;
        if (AF32) {
            float4 f0 = *(const float4*)(Afp + k0);
            float4 f1 = *(const float4*)(Afp + k0 + 4);
            av.x = (uint)f2b(f0.x) | ((uint)f2b(f0.y) << 16);
            av.y = (uint)f2b(f0.z) | ((uint)f2b(f0.w) << 16);
            av.z = (uint)f2b(f1.x) | ((uint)f2b(f1.y) << 16);
            av.w = (uint)f2b(f1.z) | ((uint)f2b(f1.w) << 16);
        } else {
            av = *(const uint4*)(Ab + k0);
        }
        uint4 bv = *(const uint4*)(Bp + k0);
        __syncthreads();
        *(uint4*)AsW = av;
        *(uint4*)BsW = bv;
        __syncthreads();
        bf16x8 af = *(const bf16x8*)AsR;
#pragma unroll
        for (int nf = 0; nf < 4; nf++) {
            bf16x8 bfv = *(const bf16x8*)(BsR + nf * 16 * LDSS);
            acc[nf] = __builtin_amdgcn_mfma_f32_16x16x32_bf16(af, bfv, acc[nf], 0, 0, 0);
        }
    }
#pragma unroll
    for (int nf = 0; nf < 4; nf++)
#pragma unroll
        for (int r = 0; r < 4; r++) {
            long m = m0 + wave * 16 + quad * 4 + r;
            long n = n0 + nf * 16 + lrow;
            float v = acc[nf][r];
            if (Cf) Cf[m * ldc + n] = v;
            else    Cb[m * ldc + n] = f2b(v);
        }
}

template <bool AF32>
__global__ void gemm_nt(const void* __restrict__ A, const ushort* __restrict__ B,
                        float* Cf, ushort* Cb, int lda, int ldb, long ldc, int K, int nTilesN)
{
    __shared__ ushort As[64 * LDSS];
    __shared__ ushort Bs[64 * LDSS];
    long m0 = (long)(blockIdx.x / nTilesN) * 64;
    long n0 = (long)(blockIdx.x % nTilesN) * 64;
    gemm64x64<AF32>(A, B, As, Bs, lda, ldb, K, Cf, Cb, ldc, m0, n0);
}

// bridge tanh + zero parity-0 ctx/denom
__global__ void btanh_kernel(const float* __restrict__ br, const float* __restrict__ bbr,
                             float* __restrict__ h, ushort* __restrict__ h_b,
                             float* __restrict__ ctx, float* __restrict__ denom)
{
    int idx = blockIdx.x * blockDim.x + threadIdx.x;  // 0..32767
    int j = idx & 511;
    float v = fast_tanh(br[idx] + bbr[j]);
    h[idx] = v;
    h_b[idx] = f2b(v);
    ctx[idx] = 0.f;
    ctx[32768 + idx] = 0.f;
    if (idx < 64) denom[idx] = 0.f;
}

extern "C" void kernel_launch(void* const* d_in, const int* in_sizes, int n_in,
                              void* d_out, int out_size, void* d_ws, size_t ws_size,
                              hipStream_t stream)
{
    (void)in_sizes; (void)n_in; (void)out_size;
    const float* trg  = (const float*)d_in[0];
    const float* enc  = (const float*)d_in[1];
    const float* encF = (const float*)d_in[2];
    const int*   mask = (const int*)d_in[3];
    const float* Wkey = (const float*)d_in[4];
    const float* Wq   = (const float*)d_in[5];
    const float* wE   = (const float*)d_in[6];
    const float* Wbr  = (const float*)d_in[7];
    const float* bbr  = (const float*)d_in[8];
    const float* Wih  = (const float*)d_in[9];
    const float* Whh  = (const float*)d_in[10];
    const float* bih  = (const float*)d_in[11];
    const float* bhh  = (const float*)d_in[12];
    const float* Wpre = (const float*)d_in[13];

    char* p = (char*)d_ws;
    auto alloc = [&](size_t bytes) { void* r = (void*)p; p += (bytes + 255) & ~(size_t)255; return r; };
    ushort* pk      = (ushort*)alloc(16777216ul * 2);
    ushort* Wkey_b  = (ushort*)alloc(524288ul * 2);
    ushort* Wq_b    = (ushort*)alloc(262144ul * 2);
    ushort* Wbr_b   = (ushort*)alloc(524288ul * 2);
    ushort* Wih_b   = (ushort*)alloc(1966080ul * 2);
    ushort* Whh_b   = (ushort*)alloc(786432ul * 2);
    ushort* Wpre_b  = (ushort*)alloc(917504ul * 2);
    float*  h       = (float*)alloc(32768ul * 4);
    ushort* h_b     = (ushort*)alloc(32768ul * 2);
    float*  br      = (float*)alloc(32768ul * 4);
    float*  q_part  = (float*)alloc(131072ul * 4);
    float*  gh_part = (float*)alloc(393216ul * 4);
    float*  pre_part= (float*)alloc(458752ul * 4);
    float*  gx_part = (float*)alloc(983040ul * 4);
    float*  ctx     = (float*)alloc(131072ul * 4);
    float*  denom   = (float*)alloc(128ul * 4);
    size_t used = (size_t)(p - (char*)d_ws);
    int useb = (used + 33554432ul * 2 <= ws_size) ? 1 : 0;
    ushort* enc_b = useb ? (ushort*)alloc(33554432ul * 2) : nullptr;

    float* out_states = (float*)d_out;
    float* out_hidden = out_states + 64l * 128 * 512;
    float* out_pre    = out_hidden + 64l * 512;

    // prelude: weight conversion + proj_key + bridge
    f2b4_kernel<<<512, 256, 0, stream>>>((const float4*)Wkey, (ushort4*)Wkey_b, 131072);
    f2b4_kernel<<<256, 256, 0, stream>>>((const float4*)Wq,   (ushort4*)Wq_b,   65536);
    f2b4_kernel<<<512, 256, 0, stream>>>((const float4*)Wbr,  (ushort4*)Wbr_b,  131072);
    f2b4_kernel<<<1920, 256, 0, stream>>>((const float4*)Wih, (ushort4*)Wih_b,  491520);
    f2b4_kernel<<<768, 256, 0, stream>>>((const float4*)Whh,  (ushort4*)Whh_b,  196608);
    f2b4_kernel<<<896, 256, 0, stream>>>((const float4*)Wpre, (ushort4*)Wpre_b, 229376);
    if (useb) {
        f2b4_kernel<<<8192, 256, 0, stream>>>((const float4*)enc, (ushort4*)enc_b, 8388608);
        gemm_nt<false><<<4096, 256, 0, stream>>>(enc_b, Wkey_b, nullptr, pk, 1024, 1024, 512, 1024, 8);
    } else {
        gemm_nt<true><<<4096, 256, 0, stream>>>(enc, Wkey_b, nullptr, pk, 1024, 1024, 512, 1024, 8);
    }
    gemm_nt<true><<<8, 256, 0, stream>>>(encF, Wbr_b, br, nullptr, 1024, 1024, 512, 1024, 8);
    btanh_kernel<<<128, 256, 0, stream>>>(br, bbr, h, h_b, ctx, denom);

    PArgs pa;
    pa.trg = trg; pa.encf = enc; pa.enc_b = enc_b; pa.useb = useb;
    pa.mask = mask; pa.pk = pk; pa.wE = wE;
    pa.Wq = Wq_b; pa.Whh = Whh_b; pa.Wih = Wih_b; pa.Wpre = Wpre_b;
    pa.bih = bih; pa.bhh = bhh;
    pa.h = h; pa.h_b = h_b;
    pa.q_part = q_part; pa.gh_part = gh_part; pa.pre_part = pre_part; pa.gx_part = gx_part;
    pa.ctx = ctx; pa.denom = denom;
    pa.out_states = out_states; pa.out_hidden = out_hidden; pa.out_pre = out_pre;

    int coopAttr = 0;
    hipDeviceGetAttribute(&coopAttr, hipDeviceAttributeCooperativeLaunch, 0);
    hipError_t ce = hipErrorUnknown;
    if (coopAttr) {
        void* kargs[] = { (void*)&pa };
        ce = hipLaunchCooperativeKernel((const void*)decoder_coop,
                                        dim3(GRID), dim3(256), kargs, 0, stream);
    }
    if (ce != hipSuccess) {
        for (int t = 0; t < 128; t++) {
            kA<<<240, 256, 0, stream>>>(pa, t);
            kB<<<512, 256, 0, stream>>>(pa, t);
            kC<<<240, 256, 0, stream>>>(pa, t);
            kD<<<256, 256, 0, stream>>>(pa, t);
        }
        kA<<<240, 256, 0, stream>>>(pa, 128);
        kF<<<128, 256, 0, stream>>>(pa);
    }
}

// Round 5
// 6400.935 us; speedup vs baseline: 6.1715x; 6.1715x over previous
//
#include <hip/hip_runtime.h>

// DecoderModule: B=64, T=128, S=512, E=256, H=512, 2H=1024, GRU_IN=1280
// fp32 I/O; bf16 MFMA internally. Multi-kernel graph, 4 nodes/step:
//   kQGH (q,gh) -> kATT (e+exp+ctx atomics) -> kGX (gx ctx-part) -> kGATE.
// pre_out deferred to one post-loop GEMM; gx x-part precomputed for all t.

#define LDSS 40

typedef short bf16x8 __attribute__((ext_vector_type(8)));
typedef float f32x4 __attribute__((ext_vector_type(4)));

__device__ inline ushort f2b(float f) {
    unsigned int u = __float_as_uint(f);
    return (ushort)((u + 0x7FFFu + ((u >> 16) & 1u)) >> 16);
}
__device__ inline float b2f(ushort u) {
    return __uint_as_float(((unsigned int)u) << 16);
}
__device__ inline float fast_tanh(float x) {
    x = fminf(fmaxf(x, -15.f), 15.f);
    float ex = __expf(2.f * x);
    return (ex - 1.f) / (ex + 1.f);
}
__device__ inline bf16x8 packA(const float* p, float s) {
    float4 f0 = *(const float4*)p;
    float4 f1 = *(const float4*)(p + 4);
    bf16x8 r;
    r[0] = (short)f2b(f0.x * s); r[1] = (short)f2b(f0.y * s);
    r[2] = (short)f2b(f0.z * s); r[3] = (short)f2b(f0.w * s);
    r[4] = (short)f2b(f1.x * s); r[5] = (short)f2b(f1.y * s);
    r[6] = (short)f2b(f1.z * s); r[7] = (short)f2b(f1.w * s);
    return r;
}
__device__ inline uint4 pack8u(const float* p) {
    float4 f0 = *(const float4*)p;
    float4 f1 = *(const float4*)(p + 4);
    uint4 av;
    av.x = (uint)f2b(f0.x) | ((uint)f2b(f0.y) << 16);
    av.y = (uint)f2b(f0.z) | ((uint)f2b(f0.w) << 16);
    av.z = (uint)f2b(f1.x) | ((uint)f2b(f1.y) << 16);
    av.w = (uint)f2b(f1.z) | ((uint)f2b(f1.w) << 16);
    return av;
}

// one wave: D[16m x 64n] += A[16,k] * W[n,k]^T over k in [kb,ke)
// layouts (gfx950, verified r2-r4): A[m=lrow][k=quad*8+j], B[n=lrow][k=quad*8+j],
// D[row=quad*4+r][col=nf*16+lrow]
template <class AG>
__device__ __forceinline__ void wave_tile(f32x4 acc[4], AG getA,
                                          const ushort* __restrict__ W, int ldw,
                                          int n0, int kb, int ke, int lrow, int quad)
{
    for (int k = kb; k < ke; k += 32) {
        int kk = k + quad * 8;
        bf16x8 av = getA(kk);
        const ushort* wp = W + (long)(n0 + lrow) * ldw + kk;
#pragma unroll
        for (int nf = 0; nf < 4; nf++) {
            bf16x8 bv = *(const bf16x8*)(wp + (long)(nf * 16) * ldw);
            acc[nf] = __builtin_amdgcn_mfma_f32_16x16x32_bf16(av, bv, acc[nf], 0, 0, 0);
        }
    }
}

__device__ __forceinline__ void store_part(float* P, f32x4 acc[4],
                                           int m0, int n0, int ldc, int lrow, int quad)
{
#pragma unroll
    for (int nf = 0; nf < 4; nf++)
#pragma unroll
        for (int r = 0; r < 4; r++)
            P[(m0 + quad * 4 + r) * ldc + (n0 + nf * 16 + lrow)] = acc[nf][r];
}

// ------------------------- per-step kernels ---------------------------------

// q = h@Wq^T (32 wave-jobs), gh = h@Whh^T (96 wave-jobs). Plain stores.
__global__ __launch_bounds__(256) void kQGH(const ushort* __restrict__ h_b,
                                            const ushort* __restrict__ Wq,
                                            const ushort* __restrict__ Whh,
                                            float* __restrict__ q, float* __restrict__ gh)
{
    int tid = threadIdx.x, wave = tid >> 6, lane = tid & 63;
    int lrow = lane & 15, quad = lane >> 4;
    int gw = blockIdx.x * 4 + wave;    // 0..127
    f32x4 acc[4];
#pragma unroll
    for (int i = 0; i < 4; i++) acc[i] = f32x4{0.f, 0.f, 0.f, 0.f};
    if (gw < 32) {
        int nt = gw & 7, ms = gw >> 3;
        const ushort* A = h_b + (ms * 16 + lrow) * 512;
        wave_tile(acc, [&](int kk) { return *(const bf16x8*)(A + kk); },
                  Wq, 512, nt * 64, 0, 512, lrow, quad);
        store_part(q, acc, ms * 16, nt * 64, 512, lrow, quad);
    } else {
        int j = gw - 32, nt = j % 24, ms = j / 24;
        const ushort* A = h_b + (ms * 16 + lrow) * 512;
        wave_tile(acc, [&](int kk) { return *(const bf16x8*)(A + kk); },
                  Whh, 512, nt * 64, 0, 512, lrow, quad);
        store_part(gh, acc, ms * 16, nt * 64, 1536, lrow, quad);
    }
}

// Fused attention: block (b, sc of 8) covers 64 s-rows. e -> exp -> partial
// ctx/denom accumulated by atomics into parity buffer t&1.
__global__ __launch_bounds__(512) void kATT(const ushort* __restrict__ pk,
                                            const float* __restrict__ q,
                                            const float* __restrict__ wE,
                                            const int* __restrict__ mask,
                                            const ushort* __restrict__ enc_b,
                                            const float* __restrict__ encf, int useb,
                                            float* __restrict__ ctx,
                                            float* __restrict__ denom, int t)
{
    __shared__ float sh_q[512];
    __shared__ float sh_w[512];
    __shared__ float sh_p[64];
    __shared__ float sh_red[8];
    __shared__ float part[2048];
    int b = blockIdx.x >> 3, sc = blockIdx.x & 7;
    int tid = threadIdx.x, wave = tid >> 6, lane = tid & 63;
    int par = t & 1;
    sh_q[tid] = q[b * 512 + tid];
    sh_w[tid] = wE[tid];
    __syncthreads();
    float wsum = 0.f;
    for (int i = 0; i < 8; i++) {
        int sl = wave * 8 + i;
        int s = sc * 64 + sl;
        const ushort* pkp = pk + ((long)(b * 512 + s) << 9) + lane * 8;
        bf16x8 pv = *(const bf16x8*)pkp;
        float acc = 0.f;
#pragma unroll
        for (int j = 0; j < 8; j++)
            acc += fast_tanh(sh_q[lane * 8 + j] + b2f((ushort)pv[j])) * sh_w[lane * 8 + j];
#pragma unroll
        for (int off = 32; off; off >>= 1) acc += __shfl_xor(acc, off);
        if (lane == 0) {
            float p = (mask[b * 512 + s] != 0) ? __expf(acc) : 0.f;
            sh_p[sl] = p;
            wsum += p;
        }
    }
    if (lane == 0) sh_red[wave] = wsum;
    __syncthreads();
    if (tid == 0) {
        float dsum = 0.f;
#pragma unroll
        for (int i = 0; i < 8; i++) dsum += sh_red[i];
        atomicAdd(&denom[par * 64 + b], dsum);
    }
    // context partial: threads split (s half, d quad)
    int sh = tid >> 8, dq = tid & 255;
    int d = dq * 4;
    float c0 = 0.f, c1 = 0.f, c2 = 0.f, c3 = 0.f;
    if (useb) {
        const ushort* ep = enc_b + ((long)b << 19) + (long)(sc * 64 + sh * 32) * 1024 + d;
#pragma unroll 4
        for (int s2 = 0; s2 < 32; s2++) {
            float p = sh_p[sh * 32 + s2];
            ushort4 ev = *(const ushort4*)(ep + (long)s2 * 1024);
            c0 += p * b2f(ev.x); c1 += p * b2f(ev.y);
            c2 += p * b2f(ev.z); c3 += p * b2f(ev.w);
        }
    } else {
        const float* ep = encf + ((long)b << 19) + (long)(sc * 64 + sh * 32) * 1024 + d;
#pragma unroll 4
        for (int s2 = 0; s2 < 32; s2++) {
            float p = sh_p[sh * 32 + s2];
            float4 ev = *(const float4*)(ep + (long)s2 * 1024);
            c0 += p * ev.x; c1 += p * ev.y; c2 += p * ev.z; c3 += p * ev.w;
        }
    }
    *(float4*)&part[sh * 1024 + d] = float4{c0, c1, c2, c3};
    __syncthreads();
    if (tid < 256) {
        int d2 = tid * 4;
        float4 x0 = *(float4*)&part[d2];
        float4 x1 = *(float4*)&part[1024 + d2];
        float* cp = ctx + par * 65536 + b * 1024 + d2;
        atomicAdd(cp,     x0.x + x1.x);
        atomicAdd(cp + 1, x0.y + x1.y);
        atomicAdd(cp + 2, x0.z + x1.z);
        atomicAdd(cp + 3, x0.w + x1.w);
    }
}

// gx ctx-part: K=1024 split 4x256, 384 wave-jobs. Plain stores to gx_part[4].
__global__ __launch_bounds__(256) void kGX(const float* __restrict__ ctx,
                                           const float* __restrict__ denom,
                                           const ushort* __restrict__ Wih,
                                           float* __restrict__ gx_part, int t)
{
    int tid = threadIdx.x, wave = tid >> 6, lane = tid & 63;
    int lrow = lane & 15, quad = lane >> 4;
    int gw = blockIdx.x * 4 + wave;   // 0..383
    int nt = gw % 24, ms = (gw / 24) & 3, kc = gw / 96;
    int par = t & 1;
    int m = ms * 16 + lrow;
    float inv = 1.f / denom[par * 64 + m];
    const float* src = ctx + par * 65536 + m * 1024;
    f32x4 acc[4];
#pragma unroll
    for (int i = 0; i < 4; i++) acc[i] = f32x4{0.f, 0.f, 0.f, 0.f};
    wave_tile(acc, [&](int kk) { return packA(src + kk, inv); },
              Wih + 256, 1280, nt * 64, kc * 256, kc * 256 + 256, lrow, quad);
    store_part(gx_part + kc * 98304, acc, ms * 16, nt * 64, 1536, lrow, quad);
}

// gates + h update + out_states + ctx_all(bf16, normalized) + zero next parity
__global__ __launch_bounds__(256) void kGATE(const float* __restrict__ gx_part,
                                             const ushort* __restrict__ gx_x,
                                             const float* __restrict__ gh,
                                             const float* __restrict__ bih,
                                             const float* __restrict__ bhh,
                                             float* __restrict__ h, ushort* __restrict__ h_b,
                                             float* __restrict__ out_states,
                                             float* __restrict__ out_hidden,
                                             ushort* __restrict__ ctx_all,
                                             float* __restrict__ ctx,
                                             float* __restrict__ denom, int t)
{
    int idx = blockIdx.x * 256 + threadIdx.x;   // 0..32767
    int b = idx >> 9, j = idx & 511;
    const ushort* gxx = gx_x + ((long)(b * 128 + t)) * 1536 + j;
    float rx = b2f(gxx[0]), zx = b2f(gxx[512]), nx = b2f(gxx[1024]);
    const float* gp = gx_part + b * 1536 + j;
#pragma unroll
    for (int kc = 0; kc < 4; kc++) {
        rx += gp[kc * 98304];
        zx += gp[kc * 98304 + 512];
        nx += gp[kc * 98304 + 1024];
    }
    const float* ghp = gh + b * 1536 + j;
    float rh = ghp[0] + bhh[j];
    float zh = ghp[512] + bhh[j + 512];
    float nh = ghp[1024] + bhh[j + 1024];
    rx += bih[j]; zx += bih[j + 512]; nx += bih[j + 1024];
    float r = 1.f / (1.f + __expf(-(rx + rh)));
    float z = 1.f / (1.f + __expf(-(zx + zh)));
    float n = fast_tanh(nx + r * nh);
    float hn = (1.f - z) * n + z * h[idx];
    h[idx] = hn;
    h_b[idx] = f2b(hn);
    out_states[((long)b * 128 + t) * 512 + j] = hn;
    if (t == 127) out_hidden[idx] = hn;
    // normalized ctx snapshot (for deferred pre GEMM) + zero next parity
    int par = t & 1, np = par ^ 1;
    int d2 = idx * 2;
    int b2 = d2 >> 10, d = d2 & 1023;
    float inv = 1.f / denom[par * 64 + b2];
    const float* cp = ctx + par * 65536 + b2 * 1024 + d;
    ushort* ca = ctx_all + ((long)(b2 * 128 + t)) * 1024 + d;
    ca[0] = f2b(cp[0] * inv);
    ca[1] = f2b(cp[1] * inv);
    float* zp = ctx + np * 65536 + b2 * 1024 + d;
    zp[0] = 0.f; zp[1] = 0.f;
    if (idx < 64) denom[np * 64 + idx] = 0.f;
}

// h0 = tanh(bridge) + zero both ctx parities + denom
__global__ __launch_bounds__(256) void kINIT(const float* __restrict__ br,
                                             const float* __restrict__ bbr,
                                             float* __restrict__ h, ushort* __restrict__ h_b,
                                             float* __restrict__ ctx, float* __restrict__ denom)
{
    int idx = blockIdx.x * 256 + threadIdx.x;   // 0..32767
    int j = idx & 511;
    float v = fast_tanh(br[idx] + bbr[j]);
    h[idx] = v;
    h_b[idx] = f2b(v);
    ctx[idx] = 0.f;
    ctx[32768 + idx] = 0.f;
    ctx[65536 + idx] = 0.f;
    ctx[98304 + idx] = 0.f;
    if (idx < 128) denom[idx] = 0.f;
}

// Deferred pre-output GEMM: out_pre[m,:] = [x_m | h_m | ctx_m] @ Wpre^T
// m = b*128+t; all three A sources are m-row-contiguous. M=8192,N=512,K=1792.
__global__ __launch_bounds__(256) void kPRE(const float* __restrict__ trg,
                                            const float* __restrict__ hs,
                                            const ushort* __restrict__ ctx_all,
                                            const ushort* __restrict__ Wpre,
                                            float* __restrict__ out_pre)
{
    __shared__ ushort As[64 * LDSS];
    __shared__ ushort Bs[64 * LDSS];
    int tid = threadIdx.x, wave = tid >> 6, lane = tid & 63;
    int row = tid >> 2, kcol = (tid & 3) * 8;
    int lrow = lane & 15, quad = lane >> 4;
    long m0 = (long)(blockIdx.x >> 3) * 64, n0 = (long)(blockIdx.x & 7) * 64;
    long m = m0 + row;
    f32x4 acc[4];
#pragma unroll
    for (int i = 0; i < 4; i++) acc[i] = f32x4{0.f, 0.f, 0.f, 0.f};
    const ushort* Bp = Wpre + (n0 + row) * 1792 + kcol;
    for (int k0 = 0; k0 < 1792; k0 += 32) {
        int k = k0 + kcol;
        uint4 av;
        if (k < 256)      av = pack8u(trg + m * 256 + k);
        else if (k < 768) av = pack8u(hs + m * 512 + (k - 256));
        else              av = *(const uint4*)(ctx_all + m * 1024 + (k - 768));
        uint4 bv = *(const uint4*)(Bp + k0);
        __syncthreads();
        *(uint4*)(As + row * LDSS + kcol) = av;
        *(uint4*)(Bs + row * LDSS + kcol) = bv;
        __syncthreads();
        bf16x8 af = *(const bf16x8*)(As + (wave * 16 + lrow) * LDSS + quad * 8);
#pragma unroll
        for (int nf = 0; nf < 4; nf++) {
            bf16x8 bv8 = *(const bf16x8*)(Bs + lrow * LDSS + quad * 8 + nf * 16 * LDSS);
            acc[nf] = __builtin_amdgcn_mfma_f32_16x16x32_bf16(af, bv8, acc[nf], 0, 0, 0);
        }
    }
#pragma unroll
    for (int nf = 0; nf < 4; nf++)
#pragma unroll
        for (int r = 0; r < 4; r++)
            out_pre[(m0 + wave * 16 + quad * 4 + r) * 512 + n0 + nf * 16 + lrow] = acc[nf][r];
}

// ------------------------- prelude kernels -----------------------------------
__global__ void f2b4_kernel(const float4* __restrict__ in, ushort4* __restrict__ out, int n4) {
    int i = blockIdx.x * blockDim.x + threadIdx.x;
    int stride = gridDim.x * blockDim.x;
    for (; i < n4; i += stride) {
        float4 v = in[i];
        ushort4 o;
        o.x = f2b(v.x); o.y = f2b(v.y); o.z = f2b(v.z); o.w = f2b(v.w);
        out[i] = o;
    }
}

template <bool AF32>
__global__ void gemm_nt(const void* __restrict__ Av, const ushort* __restrict__ B,
                        float* Cf, ushort* Cb, int lda, int ldb, long ldc, int K, int nTilesN)
{
    __shared__ ushort As[64 * LDSS];
    __shared__ ushort Bs[64 * LDSS];
    int tid = threadIdx.x, wave = tid >> 6, lane = tid & 63;
    int row = tid >> 2, kcol = (tid & 3) * 8;
    int lrow = lane & 15, quad = lane >> 4;
    long m0 = (long)(blockIdx.x / nTilesN) * 64;
    long n0 = (long)(blockIdx.x % nTilesN) * 64;
    f32x4 acc[4];
#pragma unroll
    for (int i = 0; i < 4; i++) acc[i] = f32x4{0.f, 0.f, 0.f, 0.f};
    const ushort* Ab  = (const ushort*)Av + (m0 + row) * (long)lda + kcol;
    const float*  Afp = (const float*)Av + (m0 + row) * (long)lda + kcol;
    const ushort* Bp  = B + (n0 + row) * (long)ldb + kcol;
    for (int k0 = 0; k0 < K; k0 += 32) {
        uint4 av;
        if (AF32) av = pack8u(Afp + k0);
        else      av = *(const uint4*)(Ab + k0);
        uint4 bv = *(const uint4*)(Bp + k0);
        __syncthreads();
        *(uint4*)(As + row * LDSS + kcol) = av;
        *(uint4*)(Bs + row * LDSS + kcol) = bv;
        __syncthreads();
        bf16x8 af = *(const bf16x8*)(As + (wave * 16 + lrow) * LDSS + quad * 8);
#pragma unroll
        for (int nf = 0; nf < 4; nf++) {
            bf16x8 bv8 = *(const bf16x8*)(Bs + lrow * LDSS + quad * 8 + nf * 16 * LDSS);
            acc[nf] = __builtin_amdgcn_mfma_f32_16x16x32_bf16(af, bv8, acc[nf], 0, 0, 0);
        }
    }
#pragma unroll
    for (int nf = 0; nf < 4; nf++)
#pragma unroll
        for (int r = 0; r < 4; r++) {
            long mm = m0 + wave * 16 + quad * 4 + r;
            long nn = n0 + nf * 16 + lrow;
            float v = acc[nf][r];
            if (Cf) Cf[mm * ldc + nn] = v;
            else    Cb[mm * ldc + nn] = f2b(v);
        }
}

extern "C" void kernel_launch(void* const* d_in, const int* in_sizes, int n_in,
                              void* d_out, int out_size, void* d_ws, size_t ws_size,
                              hipStream_t stream)
{
    (void)in_sizes; (void)n_in; (void)out_size;
    const float* trg  = (const float*)d_in[0];
    const float* enc  = (const float*)d_in[1];
    const float* encF = (const float*)d_in[2];
    const int*   mask = (const int*)d_in[3];
    const float* Wkey = (const float*)d_in[4];
    const float* Wq   = (const float*)d_in[5];
    const float* wE   = (const float*)d_in[6];
    const float* Wbr  = (const float*)d_in[7];
    const float* bbr  = (const float*)d_in[8];
    const float* Wih  = (const float*)d_in[9];
    const float* Whh  = (const float*)d_in[10];
    const float* bih  = (const float*)d_in[11];
    const float* bhh  = (const float*)d_in[12];
    const float* Wpre = (const float*)d_in[13];

    char* p = (char*)d_ws;
    auto alloc = [&](size_t bytes) { void* r = (void*)p; p += (bytes + 255) & ~(size_t)255; return r; };
    ushort* pk       = (ushort*)alloc(16777216ul * 2);   // [64*512,512] bf16
    ushort* Wkey_b   = (ushort*)alloc(524288ul * 2);
    ushort* Wq_b     = (ushort*)alloc(262144ul * 2);
    ushort* Wbr_b    = (ushort*)alloc(524288ul * 2);
    ushort* Wih_b    = (ushort*)alloc(1966080ul * 2);
    ushort* Whh_b    = (ushort*)alloc(786432ul * 2);
    ushort* Wpre_b   = (ushort*)alloc(917504ul * 2);
    ushort* gx_x_all = (ushort*)alloc(12582912ul * 2);   // [8192,1536] bf16
    ushort* ctx_all  = (ushort*)alloc(8388608ul * 2);    // [8192,1024] bf16
    float*  h        = (float*)alloc(32768ul * 4);
    ushort* h_b      = (ushort*)alloc(32768ul * 2);
    float*  br       = (float*)alloc(32768ul * 4);
    float*  q        = (float*)alloc(32768ul * 4);
    float*  gh       = (float*)alloc(98304ul * 4);
    float*  gx_part  = (float*)alloc(393216ul * 4);      // [4][64][1536]
    float*  ctx      = (float*)alloc(131072ul * 4);      // [2][64][1024]
    float*  denom    = (float*)alloc(128ul * 4);
    size_t used = (size_t)(p - (char*)d_ws);
    int useb = (used + 33554432ul * 2 <= ws_size) ? 1 : 0;
    ushort* enc_b = useb ? (ushort*)alloc(33554432ul * 2) : nullptr;

    float* out_states = (float*)d_out;                 // [64,128,512]
    float* out_hidden = out_states + 64l * 128 * 512;  // [1,64,512]
    float* out_pre    = out_hidden + 64l * 512;        // [64,128,512]

    // prelude: conversions, proj_key, bridge, gx_x, init
    f2b4_kernel<<<512, 256, 0, stream>>>((const float4*)Wkey, (ushort4*)Wkey_b, 131072);
    f2b4_kernel<<<256, 256, 0, stream>>>((const float4*)Wq,   (ushort4*)Wq_b,   65536);
    f2b4_kernel<<<512, 256, 0, stream>>>((const float4*)Wbr,  (ushort4*)Wbr_b,  131072);
    f2b4_kernel<<<1920, 256, 0, stream>>>((const float4*)Wih, (ushort4*)Wih_b,  491520);
    f2b4_kernel<<<768, 256, 0, stream>>>((const float4*)Whh,  (ushort4*)Whh_b,  196608);
    f2b4_kernel<<<896, 256, 0, stream>>>((const float4*)Wpre, (ushort4*)Wpre_b, 229376);
    if (useb) {
        f2b4_kernel<<<8192, 256, 0, stream>>>((const float4*)enc, (ushort4*)enc_b, 8388608);
        gemm_nt<false><<<4096, 256, 0, stream>>>(enc_b, Wkey_b, nullptr, pk, 1024, 1024, 512, 1024, 8);
    } else {
        gemm_nt<true><<<4096, 256, 0, stream>>>(enc, Wkey_b, nullptr, pk, 1024, 1024, 512, 1024, 8);
    }
    gemm_nt<true><<<8, 256, 0, stream>>>(encF, Wbr_b, br, nullptr, 1024, 1024, 512, 1024, 8);
    // gx_x_all = trg @ Wih[:, 0:256]^T   (M=8192, N=1536, K=256) -> bf16
    gemm_nt<true><<<3072, 256, 0, stream>>>(trg, Wih_b, nullptr, gx_x_all, 256, 1280, 1536, 256, 24);
    kINIT<<<128, 256, 0, stream>>>(br, bbr, h, h_b, ctx, denom);

    for (int t = 0; t < 128; t++) {
        kQGH<<<32, 256, 0, stream>>>(h_b, Wq_b, Whh_b, q, gh);
        kATT<<<512, 512, 0, stream>>>(pk, q, wE, mask, enc_b, enc, useb, ctx, denom, t);
        kGX<<<96, 256, 0, stream>>>(ctx, denom, Wih_b, gx_part, t);
        kGATE<<<128, 256, 0, stream>>>(gx_part, gx_x_all, gh, bih, bhh, h, h_b,
                                       out_states, out_hidden, ctx_all, ctx, denom, t);
    }
    // deferred pre-output GEMM over all timesteps
    kPRE<<<1024, 256, 0, stream>>>(trg, out_states, ctx_all, Wpre_b, out_pre);
}